// Round 1
// baseline (540.403 us; speedup 1.0000x reference)
//
#include <hip/hip_runtime.h>
#include <cstdint>

typedef unsigned long long u64;
typedef unsigned int u32;

#define NB 4096
#define NW 64            // 64-bit words per mask row
#define MM 20
#define HH 16
#define COND_THRES 0.2f
#define IOU_THRES 0.3f
#define PI_F  3.14159265358979323846f
#define PI4_F 0.78539816339744830962f

// ---- workspace layout (bytes), total ~2.4 MB ----
#define WS_KEYS    0                           // u64[NB]
#define WS_MASK    32768                       // u64[NB*NW] = 2 MiB
#define WS_BOX9S   (WS_MASK + NB*NW*8)         // float[NB*9]
#define WS_BEVS    (WS_BOX9S + NB*9*4)         // float4[NB]
#define WS_SCORES  (WS_BEVS + NB*16)           // float[NB]
#define WS_LABELS  (WS_SCORES + NB*4)          // int[NB]
#define WS_SUPSTEP (WS_LABELS + NB*4)          // int[NB]

// ---------- K1: sort keys. Ascending sort on (~score_bits << 12) | idx
// reproduces jnp.argsort(-where(valid,score,-inf)) stable semantics:
// descending score, ties by original idx ascending, invalid last in idx order.
__global__ void k_keys(const float* __restrict__ scores, u64* __restrict__ keys) {
  int i = blockIdx.x * blockDim.x + threadIdx.x;
  if (i >= NB) return;
  float s = scores[i];
  u32 sb = (s > COND_THRES) ? __float_as_uint(s) : 0u;   // nonneg floats: bits are order-monotonic
  keys[i] = ((u64)(sb ^ 0xFFFFFFFFu) << 12) | (u64)i;
}

// ---------- K2: single-block bitonic sort of 4096 u64 keys
__global__ void __launch_bounds__(1024) k_sort(u64* __restrict__ keys) {
  __shared__ u64 k[NB];
  for (int t = threadIdx.x; t < NB; t += 1024) k[t] = keys[t];
  __syncthreads();
  for (int len = 2; len <= NB; len <<= 1) {
    for (int s = len >> 1; s > 0; s >>= 1) {
      for (int idx = threadIdx.x; idx < NB; idx += 1024) {
        int j = idx ^ s;
        if (j > idx) {
          bool up = ((idx & len) == 0);
          u64 a = k[idx], b = k[j];
          if ((a > b) == up) { k[idx] = b; k[j] = a; }
        }
      }
      __syncthreads();
    }
  }
  for (int t = threadIdx.x; t < NB; t += 1024) keys[t] = k[t];
}

// ---------- K3: gather sorted arrays + compute axis-aligned BEV boxes
__global__ void k_gather(const u64* __restrict__ keys, const float* __restrict__ boxes9,
                         const float* __restrict__ scores, const int* __restrict__ labels,
                         float* __restrict__ box9s, float4* __restrict__ bevs,
                         float* __restrict__ scoress, int* __restrict__ labelss) {
  #pragma clang fp contract(off)
  int r = blockIdx.x * blockDim.x + threadIdx.x;
  if (r >= NB) return;
  int idx = (int)(keys[r] & 0xFFFu);
  float b[9];
  #pragma unroll
  for (int f = 0; f < 9; ++f) b[f] = boxes9[idx * 9 + f];
  #pragma unroll
  for (int f = 0; f < 9; ++f) box9s[r * 9 + f] = b[f];
  // match reference f32 op order exactly (contract off: no fma fusion)
  float ang = b[6] - floorf(b[6] / PI_F + 0.5f) * PI_F;
  bool sw = fabsf(ang) >= PI4_F;
  float dx = sw ? b[4] : b[3];
  float dy = sw ? b[3] : b[4];
  bevs[r] = make_float4(b[0] - dx * 0.5f, b[1] - dy * 0.5f,
                        b[0] + dx * 0.5f, b[1] + dy * 0.5f);
  scoress[r] = scores[idx];
  labelss[r] = labels[idx];
}

// ---------- K4: pairwise over-matrix, bit-packed. mask[i*64 + w] bit b <=> j = w*64+b
__global__ void __launch_bounds__(64) k_mask(const float4* __restrict__ bevs,
                                             const int* __restrict__ labelss,
                                             u64* __restrict__ mask) {
  #pragma clang fp contract(off)
  __shared__ float4 bj[64];
  __shared__ int lj[64];
  int t = threadIdx.x;
  int jt = blockIdx.x;   // column tile (word index)
  int it = blockIdx.y;   // row tile
  bj[t] = bevs[jt * 64 + t];
  lj[t] = labelss[jt * 64 + t];
  int i = it * 64 + t;
  float4 a = bevs[i];
  int la = labelss[i];
  float area_a = (a.z - a.x) * (a.w - a.y);
  __syncthreads();
  u64 w = 0;
  #pragma unroll 8
  for (int kk = 0; kk < 64; ++kk) {
    float4 bb = bj[kk];
    float xmin = fmaxf(a.x, bb.x), ymin = fmaxf(a.y, bb.y);
    float xmax = fminf(a.z, bb.z), ymax = fminf(a.w, bb.w);
    float inter = fmaxf(xmax - xmin, 0.0f) * fmaxf(ymax - ymin, 0.0f);
    float area_b = (bb.z - bb.x) * (bb.w - bb.y);
    float iou = inter / fmaxf(area_a + area_b - inter, 1e-6f);
    if ((iou > IOU_THRES) && (la == lj[kk])) w |= (1ull << kk);
  }
  mask[(u64)i * NW + jt] = w;
}

// ---------- K5: serial suppression resolution (1 block). Wave 0 owns the
// 4096-bit suppressed mask (one u64 per lane); waves 1..3 stage mask rows
// into a double-buffered LDS chunk. Records supstep[j] = step that first
// suppressed j (active boxes self-suppress at their own step => kept iff
// supstep[j]==j), -1 if never (invalid boxes).
#define CHUNK 32
__global__ void __launch_bounds__(256) k_resolve(const u64* __restrict__ mask,
                                                 const float* __restrict__ scoress,
                                                 int* __restrict__ supstep) {
  __shared__ u64 rowbuf[2][CHUNK * 64];     // 2 x 16 KB
  __shared__ unsigned short sstep[NB];      // 8 KB
  int tid = threadIdx.x;
  int lane = tid & 63;
  int wave = tid >> 6;
  for (int t = tid; t < NB; t += 256) sstep[t] = 0xFFFFu;
  for (int t = tid; t < CHUNK * 64; t += 256) rowbuf[0][t] = mask[t];
  u64 sup = 0;
  if (wave == 0) {
    #pragma unroll 8
    for (int b = 0; b < 64; ++b) {
      float s = scoress[(lane << 6) | b];
      if (!(s > COND_THRES)) sup |= (1ull << b);   // suppressed0 = ~valid
    }
  }
  __syncthreads();
  for (int c = 0; c < NB / CHUNK; ++c) {
    if (wave != 0) {
      if (c + 1 < NB / CHUNK) {
        const u64* src = mask + (u64)(c + 1) * (CHUNK * 64);
        u64* dst = rowbuf[(c + 1) & 1];
        for (int t = tid - 64; t < CHUNK * 64; t += 192) dst[t] = src[t];
      }
    } else {
      const u64* buf = rowbuf[c & 1];
      int ownerLane = (c * CHUNK) >> 6;     // constant per chunk
      bool isC = (lane == ownerLane);
      u64 cur[8];
      #pragma unroll
      for (int k = 0; k < 8; ++k) cur[k] = buf[k * 64 + lane];
      for (int g = 0; g < CHUNK / 8; ++g) {
        u64 nxt[8];
        if (g + 1 < CHUNK / 8) {
          #pragma unroll
          for (int k = 0; k < 8; ++k) nxt[k] = buf[((g + 1) * 8 + k) * 64 + lane];
        }
        #pragma unroll
        for (int k = 0; k < 8; ++k) {
          int r = g * 8 + k;
          int bitpos = ((c & 1) << 5) | r;                 // (c*CHUNK+r) & 63
          bool mybit = isC && ((sup >> bitpos) & 1ull);
          if (!__any((int)mybit)) {                        // step is active
            u64 row = cur[k];
            u64 nb = row & ~sup;
            sup |= row;
            if (nb) {
              int istep = c * CHUNK + r;
              do {
                int b = __builtin_ctzll(nb);
                nb &= nb - 1;
                sstep[(lane << 6) | b] = (unsigned short)istep;
              } while (nb);
            }
          }
        }
        if (g + 1 < CHUNK / 8) {
          #pragma unroll
          for (int k = 0; k < 8; ++k) cur[k] = nxt[k];
        }
      }
    }
    __syncthreads();
  }
  for (int t = tid; t < NB; t += 256) {
    unsigned short v = sstep[t];
    supstep[t] = (v == 0xFFFFu) ? -1 : (int)v;
  }
}

// ---------- K6: per-box merge + all outputs. One 64-thread block per sorted box.
__global__ void __launch_bounds__(64) k_merge(
    const u64* __restrict__ mask, const int* __restrict__ supstep,
    const float* __restrict__ box9s, const float* __restrict__ scoress,
    const int* __restrict__ labelss,
    const float* __restrict__ w1, const float* __restrict__ b1,
    const float* __restrict__ w2, const float* __restrict__ b2,
    const float* __restrict__ w3, const float* __restrict__ b3,
    float* __restrict__ out) {
  #pragma clang fp contract(off)
  __shared__ int candList[MM];
  __shared__ float ob[MM][7];
  __shared__ float h1[7][HH];
  __shared__ float h2[7][HH];
  __shared__ float res[7];
  int i = blockIdx.x;
  int t = threadIdx.x;
  bool active = (supstep[i] == i);
  u64 wq = 0;
  int cnt = 0;
  if (active) {
    u64 w = mask[(u64)i * NW + t];
    while (w) {
      int b = __builtin_ctzll(w);
      w &= w - 1;
      int j = (t << 6) | b;
      if (supstep[j] >= i) { wq |= (1ull << b); cnt++; }   // not suppressed before step i
    }
  }
  // wave-wide exclusive scan of per-lane candidate counts
  int incl = cnt;
  #pragma unroll
  for (int off = 1; off < 64; off <<= 1) {
    int v = __shfl_up(incl, off);
    if (t >= off) incl += v;
  }
  int excl = incl - cnt;
  int count = __shfl(incl, 63);
  bool merged = active && (count > 1);
  if (merged && wq) {
    int pos = excl;
    u64 ww = wq;
    while (ww && pos < MM) {
      int b = __builtin_ctzll(ww);
      ww &= ww - 1;
      candList[pos++] = (t << 6) | b;
    }
  }
  __syncthreads();
  if (merged) {
    int nc = count < MM ? count : MM;
    if (t < MM) {
      if (t < nc) {
        int j = candList[t];
        #pragma unroll
        for (int f = 0; f < 7; ++f) ob[t][f] = box9s[j * 9 + f];
      } else {
        #pragma unroll
        for (int f = 0; f < 7; ++f) ob[t][f] = 0.0f;
      }
    }
    __syncthreads();
    for (int o = t; o < 7 * HH; o += 64) {
      int f = o >> 4, hh = o & 15;
      float acc = b1[hh];
      #pragma unroll
      for (int m = 0; m < MM; ++m) acc += ob[m][f] * w1[m * HH + hh];
      h1[f][hh] = fmaxf(acc, 0.0f);
    }
    __syncthreads();
    for (int o = t; o < 7 * HH; o += 64) {
      int f = o >> 4, oo = o & 15;
      float acc = b2[oo];
      #pragma unroll
      for (int k = 0; k < HH; ++k) acc += h1[f][k] * w2[k * HH + oo];
      h2[f][oo] = fmaxf(acc, 0.0f);
    }
    __syncthreads();
    if (t < 7) {
      float acc = b3[0];
      #pragma unroll
      for (int k = 0; k < HH; ++k) acc += h2[t][k] * w3[k];
      if (t >= 3 && t < 6) acc = fmaxf(acc, 1e-5f);  // dims clamp
      res[t] = acc;
    }
    __syncthreads();
  }
  if (t < 9) {
    float v = box9s[i * 9 + t];
    if (merged && t < 7) v = res[t];
    out[i * 9 + t] = v;
  }
  if (t == 0) {
    out[NB * 9 + i]          = scoress[i];
    out[NB * 9 + NB + i]     = (float)labelss[i];
    out[NB * 9 + 2 * NB + i] = active ? 1.0f : 0.0f;
  }
}

extern "C" void kernel_launch(void* const* d_in, const int* in_sizes, int n_in,
                              void* d_out, int out_size, void* d_ws, size_t ws_size,
                              hipStream_t stream) {
  const float* boxes9 = (const float*)d_in[0];
  const float* scores = (const float*)d_in[1];
  const int*   labels = (const int*)d_in[2];
  const float* w1 = (const float*)d_in[3];
  const float* b1 = (const float*)d_in[4];
  const float* w2 = (const float*)d_in[5];
  const float* b2 = (const float*)d_in[6];
  const float* w3 = (const float*)d_in[7];
  const float* b3 = (const float*)d_in[8];
  char* ws = (char*)d_ws;
  u64*    keys    = (u64*)(ws + WS_KEYS);
  u64*    mask    = (u64*)(ws + WS_MASK);
  float*  box9s   = (float*)(ws + WS_BOX9S);
  float4* bevs    = (float4*)(ws + WS_BEVS);
  float*  scoress = (float*)(ws + WS_SCORES);
  int*    labelss = (int*)(ws + WS_LABELS);
  int*    supstep = (int*)(ws + WS_SUPSTEP);
  float*  out     = (float*)d_out;

  hipLaunchKernelGGL(k_keys,    dim3(NB / 256), dim3(256),  0, stream, scores, keys);
  hipLaunchKernelGGL(k_sort,    dim3(1),        dim3(1024), 0, stream, keys);
  hipLaunchKernelGGL(k_gather,  dim3(NB / 256), dim3(256),  0, stream, keys, boxes9, scores, labels,
                     box9s, bevs, scoress, labelss);
  hipLaunchKernelGGL(k_mask,    dim3(64, 64),   dim3(64),   0, stream, bevs, labelss, mask);
  hipLaunchKernelGGL(k_resolve, dim3(1),        dim3(256),  0, stream, mask, scoress, supstep);
  hipLaunchKernelGGL(k_merge,   dim3(NB),       dim3(64),   0, stream, mask, supstep,
                     box9s, scoress, labelss, w1, b1, w2, b2, w3, b3, out);
}